// Round 8
// baseline (170.235 us; speedup 1.0000x reference)
//
#include <hip/hip_runtime.h>
#include <math.h>

// NeuralSplineCoupling: y[:, :3] = RQS(x[:, :3]; params = MLP([x[:,3:], c]))
//                       y[:, 3:] = x[:, 3:],  log_det = sum over 3 dims
// N = 500000, X_DIM=6, C_DIM=4, HID=128, KNOTS=16, SPLINE_DIM=47, OUT_DIM=141
//
// Round 8: NT=128, each wave owns 64 samples (4 rowblocks). B-fragments loaded
// ONCE per wave into registers (B2=128 VGPR, B3=144 VGPR; launch_bounds(128,2)
// -> 256-VGPR budget) and reused across 4 rowblocks: per-sample weight traffic
// halves vs round 7, and the reuse is loop-carried so the compiler cannot fold
// it away. Wave-private rows -> zero barriers through the MLP (in-place h).
// Layer-3 results stashed fp16-packed in regs across the aliasing barrier,
// then scattered to shp16. LDS 40.4 KB -> 4 blocks/CU.

#define TILE 128
#define NT   128
#define HID  128
#define OUTD 141
#define HS   136     // hbuf row stride (bf16): 272 B rows, bank-rotate 4
#define PRS  48      // halves per (sample,dim) p row
#define SRS  152     // halves per sample in shp (304 B, 16B-aligned)
#define BND  5.0f
#define T1   0.5413248546f   // ln(e-1): softplus(T1) = 1

typedef __bf16 bf16;
typedef _Float16 f16;
typedef __attribute__((ext_vector_type(8))) __bf16 bf16x8;
typedef __attribute__((ext_vector_type(8))) _Float16 f16x8;
typedef __attribute__((ext_vector_type(2))) _Float16 f16x2;
typedef __attribute__((ext_vector_type(4))) float f32x4;

#define W1P_ELEMS (8 * 64 * 8)
#define W2P_ELEMS (8 * 4 * 64 * 8)
#define W3P_ELEMS (9 * 4 * 64 * 8)

// LDS (bytes): hbuf [0,34816) (inputs -> h1 -> h2 in place);
// shp16 fp16 [0,38912) aliases hbuf (barrier-separated); shld [38912,40448)
#define SMEM_BYTES 40448

// One thread per 8-element B fragment; k-permutation colmap(p)=(p&7)*16+(p>>3).
__global__ void nsc_prepack(const float* __restrict__ W1, const float* __restrict__ W2,
                            const float* __restrict__ W3,
                            bf16* __restrict__ W1p, bf16* __restrict__ W2p,
                            bf16* __restrict__ W3p) {
    int f = blockIdx.x * 256 + threadIdx.x;
    int lane = f & 63, lm = lane & 15, lq = lane >> 4;
    if (f < 512) {                                   // W1: 8 tiles, identity k
        int t = f >> 6;
        int n = t * 16 + lm;
        bf16x8 pk;
        #pragma unroll
        for (int j = 0; j < 8; ++j) {
            int k = lq * 8 + j;
            pk[j] = (k < 7) ? (bf16)W1[k * HID + n] : (bf16)0.f;
        }
        *(bf16x8*)&W1p[(size_t)f * 8] = pk;
    } else if (f < 512 + 2048) {                     // W2: 8 tiles x 4 ks
        int g2 = f - 512;
        int tk = g2 >> 6, t = tk >> 2, ks = tk & 3;
        int n = t * 16 + lm;
        bf16x8 pk;
        #pragma unroll
        for (int j = 0; j < 8; ++j) {
            int p = ks * 32 + lq * 8 + j;
            int k = ((p & 7) << 4) | (p >> 3);
            pk[j] = (bf16)W2[k * HID + n];
        }
        *(bf16x8*)&W2p[(size_t)g2 * 8] = pk;
    } else if (f < 512 + 2048 + 2304) {              // W3: 9 tiles x 4 ks
        int g3 = f - 2560;
        int tk = g3 >> 6, t = tk >> 2, ks = tk & 3;
        int col = t * 16 + lm;
        bf16x8 pk;
        #pragma unroll
        for (int j = 0; j < 8; ++j) {
            int p = ks * 32 + lq * 8 + j;
            int k = ((p & 7) << 4) | (p >> 3);
            pk[j] = (col < OUTD) ? (bf16)W3[k * OUTD + col] : (bf16)0.f;
        }
        *(bf16x8*)&W3p[(size_t)g3 * 8] = pk;
    }
}

__global__ __launch_bounds__(NT, 2) void nsc_main(
    const float* __restrict__ x, const float* __restrict__ c,
    const bf16* __restrict__ W1p, const float* __restrict__ b1,
    const bf16* __restrict__ W2p, const float* __restrict__ b2,
    const bf16* __restrict__ W3p, const float* __restrict__ b3,
    float* __restrict__ out_y, float* __restrict__ out_ld, int N)
{
    __shared__ __align__(16) char smem[SMEM_BYTES];
    bf16*  hbuf  = (bf16*)smem;                 // [128][HS]: inputs -> h1 -> h2
    f16*   shp16 = (f16*)smem;                  // [128][3][PRS] fp16, aliases hbuf
    float* shld  = (float*)(smem + 38912);      // [128][3]

    const int tid  = threadIdx.x;
    const int g0   = blockIdx.x * TILE;
    const int lane = tid & 63;
    const int wv   = tid >> 6;        // 0 or 1; wave owns samples wv*64..wv*64+63
    const int lm   = lane & 15;
    const int lq   = lane >> 4;
    const int sbase = wv * 64;

    // ---- Phase 0: each lane stages its own row (wave-private; no barrier) ----
    {
        int s = sbase + lane;
        int g = g0 + s;
        float v[7];
        if (g < N) {
            v[0] = x[g * 6 + 3]; v[1] = x[g * 6 + 4]; v[2] = x[g * 6 + 5];
            v[3] = c[g * 4];     v[4] = c[g * 4 + 1];
            v[5] = c[g * 4 + 2]; v[6] = c[g * 4 + 3];
        } else {
            #pragma unroll
            for (int k = 0; k < 7; ++k) v[k] = 0.f;
        }
        bf16x8 r0 = (bf16x8){(bf16)v[0], (bf16)v[1], (bf16)v[2], (bf16)v[3],
                             (bf16)v[4], (bf16)v[5], (bf16)v[6], (bf16)0.f};
        bf16x8 z  = (bf16x8){(bf16)0.f, (bf16)0.f, (bf16)0.f, (bf16)0.f,
                             (bf16)0.f, (bf16)0.f, (bf16)0.f, (bf16)0.f};
        *(bf16x8*)&hbuf[s * HS]      = r0;
        *(bf16x8*)&hbuf[s * HS + 8]  = z;
        *(bf16x8*)&hbuf[s * HS + 16] = z;
        *(bf16x8*)&hbuf[s * HS + 24] = z;
    }

    // hoisted biases (rb-invariant per lane)
    float bb1[8], bb2[8], bb3[9];
    #pragma unroll
    for (int t = 0; t < 8; ++t) { bb1[t] = b1[t * 16 + lm]; bb2[t] = b2[t * 16 + lm]; }
    #pragma unroll
    for (int t = 0; t < 9; ++t) {
        int col = t * 16 + lm;
        bb3[t] = (col < OUTD) ? b3[col] : 0.f;
    }

    // ---- Phase 1: h1 = relu([in,0] @ W1 + b1); B1 register-resident ----
    {
        bf16x8 B1[8];
        #pragma unroll
        for (int t = 0; t < 8; ++t)
            B1[t] = *(const bf16x8*)&W1p[(size_t)(t * 64 + lane) * 8];
        #pragma unroll
        for (int rb = 0; rb < 4; ++rb) {
            const int rB = sbase + rb * 16;
            bf16x8 a = *(const bf16x8*)&hbuf[(rB + lm) * HS + lq * 8];
            f32x4 acc[8];
            #pragma unroll
            for (int t = 0; t < 8; ++t)
                acc[t] = (f32x4){bb1[t], bb1[t], bb1[t], bb1[t]};
            #pragma unroll
            for (int t = 0; t < 8; ++t)
                acc[t] = __builtin_amdgcn_mfma_f32_16x16x32_bf16(a, B1[t], acc[t], 0, 0, 0);
            #pragma unroll
            for (int r = 0; r < 4; ++r) {
                bf16x8 pk;
                #pragma unroll
                for (int t = 0; t < 8; ++t) pk[t] = (bf16)fmaxf(acc[t][r], 0.f);
                *(bf16x8*)&hbuf[(rB + lq * 4 + r) * HS + lm * 8] = pk;
            }
        }
    }

    // ---- Phase 2: h2 = relu(h1 @ W2 + b2); B2 (32 frags) register-resident ----
    {
        bf16x8 B2[32];
        #pragma unroll
        for (int i = 0; i < 32; ++i)
            B2[i] = *(const bf16x8*)&W2p[(size_t)(i * 64 + lane) * 8];
        #pragma unroll
        for (int rb = 0; rb < 4; ++rb) {
            const int rB = sbase + rb * 16;
            bf16x8 a[4];
            #pragma unroll
            for (int ks = 0; ks < 4; ++ks)
                a[ks] = *(const bf16x8*)&hbuf[(rB + lm) * HS + ks * 32 + lq * 8];
            f32x4 acc[8];
            #pragma unroll
            for (int t = 0; t < 8; ++t)
                acc[t] = (f32x4){bb2[t], bb2[t], bb2[t], bb2[t]};
            #pragma unroll
            for (int ks = 0; ks < 4; ++ks)
                #pragma unroll
                for (int t = 0; t < 8; ++t)
                    acc[t] = __builtin_amdgcn_mfma_f32_16x16x32_bf16(a[ks], B2[t * 4 + ks], acc[t], 0, 0, 0);
            #pragma unroll
            for (int r = 0; r < 4; ++r) {
                bf16x8 pk;
                #pragma unroll
                for (int t = 0; t < 8; ++t) pk[t] = (bf16)fmaxf(acc[t][r], 0.f);
                *(bf16x8*)&hbuf[(rB + lq * 4 + r) * HS + lm * 8] = pk;
            }
        }
    }

    // ---- Phase 3: p = h2 @ W3 + b3; B3 (36 frags) register-resident.
    // Results stashed fp16-packed in regs (4rb x 9t x f16x2-pairs = 72 VGPR),
    // scattered to shp16 AFTER the barrier (shp16 aliases other waves' hbuf).
    f16x2 stash[4][9][2];
    {
        bf16x8 B3[36];
        #pragma unroll
        for (int i = 0; i < 36; ++i)
            B3[i] = *(const bf16x8*)&W3p[(size_t)(i * 64 + lane) * 8];
        #pragma unroll
        for (int rb = 0; rb < 4; ++rb) {
            const int rB = sbase + rb * 16;
            bf16x8 a[4];
            #pragma unroll
            for (int ks = 0; ks < 4; ++ks)
                a[ks] = *(const bf16x8*)&hbuf[(rB + lm) * HS + ks * 32 + lq * 8];
            f32x4 acc[9];
            #pragma unroll
            for (int t = 0; t < 9; ++t)
                acc[t] = (f32x4){bb3[t], bb3[t], bb3[t], bb3[t]};
            #pragma unroll
            for (int ks = 0; ks < 4; ++ks)
                #pragma unroll
                for (int t = 0; t < 9; ++t)
                    acc[t] = __builtin_amdgcn_mfma_f32_16x16x32_bf16(a[ks], B3[t * 4 + ks], acc[t], 0, 0, 0);
            #pragma unroll
            for (int t = 0; t < 9; ++t) {
                stash[rb][t][0] = (f16x2){(f16)acc[t][0], (f16)acc[t][1]};
                stash[rb][t][1] = (f16x2){(f16)acc[t][2], (f16)acc[t][3]};
            }
        }
    }
    __syncthreads();   // all waves done with hbuf -> shp16 region is free

    // scatter stash -> shp16 [s][d][48]
    {
        int off3[9]; bool val3[9];
        #pragma unroll
        for (int t = 0; t < 9; ++t) {
            int col = t * 16 + lm;
            val3[t] = (col < OUTD);
            int d = (col >= 94) ? 2 : ((col >= 47) ? 1 : 0);
            off3[t] = d * PRS + (col - d * 47);
        }
        #pragma unroll
        for (int rb = 0; rb < 4; ++rb) {
            const int rB = sbase + rb * 16;
            #pragma unroll
            for (int t = 0; t < 9; ++t) {
                if (val3[t]) {
                    #pragma unroll
                    for (int r = 0; r < 4; ++r) {
                        int s = rB + lq * 4 + r;
                        shp16[s * SRS + off3[t]] = stash[rb][t][r >> 1][r & 1];
                    }
                }
            }
        }
    }
    __syncthreads();

    // ---- Phase 4: per (sample, dim): softmax -> bin scan -> RQS ----
    for (int pidx = tid; pidx < TILE * 3; pidx += NT) {
        const int s = pidx / 3, d = pidx - s * 3;
        const int g = g0 + s;
        if (g < N) {
            const f16* pr = &shp16[s * SRS + d * PRS];
            f16x8 v0 = *(const f16x8*)&pr[0];
            f16x8 v1 = *(const f16x8*)&pr[8];
            f16x8 v2 = *(const f16x8*)&pr[16];
            f16x8 v3 = *(const f16x8*)&pr[24];
            f16x8 v4 = *(const f16x8*)&pr[32];
            f16x8 v5 = *(const f16x8*)&pr[40];
            float wv_[16], hv[16], dl[15];
            #pragma unroll
            for (int i = 0; i < 8; ++i) {
                wv_[i] = (float)v0[i]; wv_[8 + i] = (float)v1[i];
                hv[i]  = (float)v2[i]; hv[8 + i]  = (float)v3[i];
            }
            #pragma unroll
            for (int i = 0; i < 8; ++i) dl[i] = (float)v4[i];
            #pragma unroll
            for (int i = 0; i < 7; ++i) dl[8 + i] = (float)v5[i];

            float sw = 0.f, sh = 0.f;
            #pragma unroll
            for (int i = 0; i < 16; ++i) { wv_[i] = __expf(wv_[i]); sw += wv_[i]; }
            #pragma unroll
            for (int i = 0; i < 16; ++i) { hv[i]  = __expf(hv[i]);  sh += hv[i]; }
            float cwn = 10.f * __builtin_amdgcn_rcpf(sw);
            float chn = 10.f * __builtin_amdgcn_rcpf(sh);
            #pragma unroll
            for (int i = 0; i < 16; ++i) { wv_[i] *= cwn; hv[i] *= chn; }

            float xv = x[g * 6 + d];
            bool oob = (xv <= -BND) || (xv >= BND);
            float xm = oob ? -BND : xv;

            float cumx = -BND + wv_[0], cumy = -BND + hv[0];
            float xk_b = -BND, yk_b = -BND;
            float wk = wv_[0], hk = hv[0];
            float d0l = T1, d1l = dl[0];
            #pragma unroll
            for (int i = 1; i < 16; ++i) {
                bool ge = (xm >= cumx);
                if (ge) {
                    xk_b = cumx; yk_b = cumy;
                    wk = wv_[i]; hk = hv[i];
                    d0l = dl[i - 1];
                    d1l = (i < 15) ? dl[i] : T1;
                }
                cumx += wv_[i]; cumy += hv[i];
            }
            float d0 = (d0l > 15.f) ? d0l : __logf(1.f + __expf(d0l));
            float d1 = (d1l > 15.f) ? d1l : __logf(1.f + __expf(d1l));

            float rwk = __builtin_amdgcn_rcpf(wk);
            float sk = hk * rwk;
            float relx = (xm - xk_b) * rwk;
            relx = fminf(fmaxf(relx, 0.f), 1.f);
            float r1 = relx * (1.f - relx);
            float den = sk + (d1 + d0 - 2.f * sk) * r1;
            float iden = __builtin_amdgcn_rcpf(den);
            float num = hk * (sk * relx * relx + d0 * r1);
            float y = yk_b + num * iden;
            float omr = 1.f - relx;
            float arg = d1 * relx * relx + 2.f * sk * r1 + d0 * omr * omr;
            float ratio = sk * iden;
            float ld = __logf(ratio * ratio * arg);
            if (oob) { y = xv; ld = 0.f; }

            out_y[g * 6 + d] = y;
            out_y[g * 6 + 3 + d] = x[g * 6 + 3 + d];   // upper pass-through (fp32)
            shld[s * 3 + d] = ld;
        }
    }
    __syncthreads();

    // ---- Phase 5: reduce log-det over the 3 dims ----
    {
        int g = g0 + tid;
        if (g < N)
            out_ld[g] = shld[tid * 3] + shld[tid * 3 + 1] + shld[tid * 3 + 2];
    }
}

extern "C" void kernel_launch(void* const* d_in, const int* in_sizes, int n_in,
                              void* d_out, int out_size, void* d_ws, size_t ws_size,
                              hipStream_t stream) {
    const float* x  = (const float*)d_in[0];
    const float* c  = (const float*)d_in[1];
    const float* W1 = (const float*)d_in[2];
    const float* b1 = (const float*)d_in[3];
    const float* W2 = (const float*)d_in[4];
    const float* b2 = (const float*)d_in[5];
    const float* W3 = (const float*)d_in[6];
    const float* b3 = (const float*)d_in[7];

    const int N = in_sizes[0] / 6;              // 500000
    float* out_y  = (float*)d_out;
    float* out_ld = (float*)d_out + (size_t)N * 6;

    bf16* W1p = (bf16*)d_ws;
    bf16* W2p = W1p + W1P_ELEMS;
    bf16* W3p = W2p + W2P_ELEMS;

    int nfrag = 512 + 2048 + 2304;              // 4864 fragments
    nsc_prepack<<<(nfrag + 255) / 256, 256, 0, stream>>>(W1, W2, W3, W1p, W2p, W3p);

    int nblocks = (N + TILE - 1) / TILE;        // 3907
    nsc_main<<<nblocks, NT, 0, stream>>>(x, c, W1p, b1, W2p, b2, W3p, b3,
                                         out_y, out_ld, N);
}

// Round 10
// 159.135 us; speedup vs baseline: 1.0698x; 1.0698x over previous
//
#include <hip/hip_runtime.h>
#include <math.h>

// NeuralSplineCoupling: y[:, :3] = RQS(x[:, :3]; params = MLP([x[:,3:], c]))
//                       y[:, 3:] = x[:, 3:],  log_det = sum over 3 dims
// N = 500000, X_DIM=6, C_DIM=4, HID=128, KNOTS=16, SPLINE_DIM=47, OUT_DIM=141
//
// Round 10: round-7 structure (wave owns 32 samples, zero barriers in the MLP,
// B-frags from L2, in-place h overwrite — VERIFIED GREEN at 89 us) + LDS shrink:
// inputs staged directly into hbuf rows (wave-private, in-order DS) instead of
// a separate shIn -> 39.5 KB -> 4 blocks/CU with launch_bounds(256,4).
// Round 9's n-split is reverted (unidentified log_det corruption).

#define TILE 128
#define NT   256
#define HID  128
#define OUTD 141
#define HS   136     // hbuf row stride (bf16): 272 B rows, bank-rotate 4
#define PRS  48      // halves per (sample,dim) p row
#define SRS  152     // halves per sample in shp (304 B, 16B-aligned)
#define BND  5.0f
#define T1   0.5413248546f   // ln(e-1): softplus(T1) = 1

typedef __bf16 bf16;
typedef _Float16 f16;
typedef __attribute__((ext_vector_type(8))) __bf16 bf16x8;
typedef __attribute__((ext_vector_type(8))) _Float16 f16x8;
typedef __attribute__((ext_vector_type(4))) float f32x4;

#define W1P_ELEMS (8 * 64 * 8)
#define W2P_ELEMS (8 * 4 * 64 * 8)
#define W3P_ELEMS (9 * 4 * 64 * 8)

// LDS (bytes): hbuf [0,34816) (inputs -> h1 -> h2, in place, wave-private);
// shp16 fp16 [0,38912) aliases hbuf (barrier-separated); shld [38912,40448)
#define SMEM_BYTES 40448

// One thread per 8-element B fragment; k-permutation colmap(p)=(p&7)*16+(p>>3).
__global__ void nsc_prepack(const float* __restrict__ W1, const float* __restrict__ W2,
                            const float* __restrict__ W3,
                            bf16* __restrict__ W1p, bf16* __restrict__ W2p,
                            bf16* __restrict__ W3p) {
    int f = blockIdx.x * 256 + threadIdx.x;
    int lane = f & 63, lm = lane & 15, lq = lane >> 4;
    if (f < 512) {                                   // W1: 8 tiles, identity k
        int t = f >> 6;
        int n = t * 16 + lm;
        bf16x8 pk;
        #pragma unroll
        for (int j = 0; j < 8; ++j) {
            int k = lq * 8 + j;
            pk[j] = (k < 7) ? (bf16)W1[k * HID + n] : (bf16)0.f;
        }
        *(bf16x8*)&W1p[(size_t)f * 8] = pk;
    } else if (f < 512 + 2048) {                     // W2: 8 tiles x 4 ks
        int g2 = f - 512;
        int tk = g2 >> 6, t = tk >> 2, ks = tk & 3;
        int n = t * 16 + lm;
        bf16x8 pk;
        #pragma unroll
        for (int j = 0; j < 8; ++j) {
            int p = ks * 32 + lq * 8 + j;
            int k = ((p & 7) << 4) | (p >> 3);
            pk[j] = (bf16)W2[k * HID + n];
        }
        *(bf16x8*)&W2p[(size_t)g2 * 8] = pk;
    } else if (f < 512 + 2048 + 2304) {              // W3: 9 tiles x 4 ks
        int g3 = f - 2560;
        int tk = g3 >> 6, t = tk >> 2, ks = tk & 3;
        int col = t * 16 + lm;
        bf16x8 pk;
        #pragma unroll
        for (int j = 0; j < 8; ++j) {
            int p = ks * 32 + lq * 8 + j;
            int k = ((p & 7) << 4) | (p >> 3);
            pk[j] = (col < OUTD) ? (bf16)W3[k * OUTD + col] : (bf16)0.f;
        }
        *(bf16x8*)&W3p[(size_t)g3 * 8] = pk;
    }
}

__global__ __launch_bounds__(NT, 4) void nsc_main(
    const float* __restrict__ x, const float* __restrict__ c,
    const bf16* __restrict__ W1p, const float* __restrict__ b1,
    const bf16* __restrict__ W2p, const float* __restrict__ b2,
    const bf16* __restrict__ W3p, const float* __restrict__ b3,
    float* __restrict__ out_y, float* __restrict__ out_ld, int N)
{
    __shared__ __align__(16) char smem[SMEM_BYTES];
    bf16*  hbuf  = (bf16*)smem;                 // [128][HS], k-permuted positions
    f16*   shp16 = (f16*)smem;                  // [128][3][PRS] fp16, aliases hbuf
    float* shld  = (float*)(smem + 38912);      // [128][3]

    const int tid  = threadIdx.x;
    const int g0   = blockIdx.x * TILE;
    const int lane = tid & 63;
    const int wv   = tid >> 6;        // wave id; owns samples wv*32 .. wv*32+31
    const int lm   = lane & 15;
    const int lq   = lane >> 4;
    const int sbase = wv * 32;
    const int arow0 = sbase + lm;     // A-row for rowblock 0
    const int arow1 = sbase + 16 + lm;

    // ---- Phase 0: stage inputs bf16 into hbuf positions 0..31 (wave-private,
    // identity k, zero-padded). In-order DS per wave -> no barrier. ----
    if (lane < 32) {
        int s = sbase + lane;
        int g = g0 + s;
        float v[7];
        if (g < N) {
            v[0] = x[g * 6 + 3]; v[1] = x[g * 6 + 4]; v[2] = x[g * 6 + 5];
            v[3] = c[g * 4];     v[4] = c[g * 4 + 1];
            v[5] = c[g * 4 + 2]; v[6] = c[g * 4 + 3];
        } else {
            #pragma unroll
            for (int k = 0; k < 7; ++k) v[k] = 0.f;
        }
        bf16x8 r0 = (bf16x8){(bf16)v[0], (bf16)v[1], (bf16)v[2], (bf16)v[3],
                             (bf16)v[4], (bf16)v[5], (bf16)v[6], (bf16)0.f};
        bf16x8 z  = (bf16x8){(bf16)0.f, (bf16)0.f, (bf16)0.f, (bf16)0.f,
                             (bf16)0.f, (bf16)0.f, (bf16)0.f, (bf16)0.f};
        *(bf16x8*)&hbuf[s * HS]      = r0;
        *(bf16x8*)&hbuf[s * HS + 8]  = z;
        *(bf16x8*)&hbuf[s * HS + 16] = z;
        *(bf16x8*)&hbuf[s * HS + 24] = z;
    }

    // ---- Phase 1: h1 = relu([h,0] @ W1 + b1); 2 A-rows per B-frag ----
    {
        f32x4 acc1[2][8];
        #pragma unroll
        for (int t = 0; t < 8; ++t) {
            float b = b1[t * 16 + lm];
            acc1[0][t] = (f32x4){b, b, b, b};
            acc1[1][t] = (f32x4){b, b, b, b};
        }
        bf16x8 a0 = *(const bf16x8*)&hbuf[arow0 * HS + lq * 8];
        bf16x8 a1 = *(const bf16x8*)&hbuf[arow1 * HS + lq * 8];
        #pragma unroll
        for (int t = 0; t < 8; ++t) {
            bf16x8 bf = *(const bf16x8*)&W1p[(size_t)(t * 64 + lane) * 8];
            acc1[0][t] = __builtin_amdgcn_mfma_f32_16x16x32_bf16(a0, bf, acc1[0][t], 0, 0, 0);
            acc1[1][t] = __builtin_amdgcn_mfma_f32_16x16x32_bf16(a1, bf, acc1[1][t], 0, 0, 0);
        }
        // epilogue: position p = lm*8+t holds col t*16+lm -> one b128 per (ar,r)
        #pragma unroll
        for (int ar = 0; ar < 2; ++ar)
            #pragma unroll
            for (int r = 0; r < 4; ++r) {
                bf16x8 pk;
                #pragma unroll
                for (int t = 0; t < 8; ++t) pk[t] = (bf16)fmaxf(acc1[ar][t][r], 0.f);
                int s = sbase + ar * 16 + lq * 4 + r;
                *(bf16x8*)&hbuf[s * HS + lm * 8] = pk;
            }
    }

    // ---- Phase 2: h2 = relu(h1 @ W2 + b2); in-place overwrite ----
    {
        f32x4 acc2[2][8];
        #pragma unroll
        for (int t = 0; t < 8; ++t) {
            float b = b2[t * 16 + lm];
            acc2[0][t] = (f32x4){b, b, b, b};
            acc2[1][t] = (f32x4){b, b, b, b};
        }
        #pragma unroll
        for (int ks = 0; ks < 4; ++ks) {
            bf16x8 a0 = *(const bf16x8*)&hbuf[arow0 * HS + ks * 32 + lq * 8];
            bf16x8 a1 = *(const bf16x8*)&hbuf[arow1 * HS + ks * 32 + lq * 8];
            #pragma unroll
            for (int t = 0; t < 8; ++t) {
                bf16x8 bf = *(const bf16x8*)&W2p[(size_t)((t * 4 + ks) * 64 + lane) * 8];
                acc2[0][t] = __builtin_amdgcn_mfma_f32_16x16x32_bf16(a0, bf, acc2[0][t], 0, 0, 0);
                acc2[1][t] = __builtin_amdgcn_mfma_f32_16x16x32_bf16(a1, bf, acc2[1][t], 0, 0, 0);
            }
        }
        #pragma unroll
        for (int ar = 0; ar < 2; ++ar)
            #pragma unroll
            for (int r = 0; r < 4; ++r) {
                bf16x8 pk;
                #pragma unroll
                for (int t = 0; t < 8; ++t) pk[t] = (bf16)fmaxf(acc2[ar][t][r], 0.f);
                int s = sbase + ar * 16 + lq * 4 + r;
                *(bf16x8*)&hbuf[s * HS + lm * 8] = pk;
            }
    }

    // ---- Phase 3: p = h2 @ W3 + b3 (9 tiles, 144 cols) ----
    f32x4 acc3[2][9];
    {
        #pragma unroll
        for (int t = 0; t < 9; ++t) {
            int col = t * 16 + lm;
            float b = (col < OUTD) ? b3[col] : 0.f;
            acc3[0][t] = (f32x4){b, b, b, b};
            acc3[1][t] = (f32x4){b, b, b, b};
        }
        #pragma unroll
        for (int ks = 0; ks < 4; ++ks) {
            bf16x8 a0 = *(const bf16x8*)&hbuf[arow0 * HS + ks * 32 + lq * 8];
            bf16x8 a1 = *(const bf16x8*)&hbuf[arow1 * HS + ks * 32 + lq * 8];
            #pragma unroll
            for (int t = 0; t < 9; ++t) {
                bf16x8 bf = *(const bf16x8*)&W3p[(size_t)((t * 4 + ks) * 64 + lane) * 8];
                acc3[0][t] = __builtin_amdgcn_mfma_f32_16x16x32_bf16(a0, bf, acc3[0][t], 0, 0, 0);
                acc3[1][t] = __builtin_amdgcn_mfma_f32_16x16x32_bf16(a1, bf, acc3[1][t], 0, 0, 0);
            }
        }
    }
    __syncthreads();   // all waves done reading hbuf -> shp16 region is free

    // epilogue: scatter p (fp16) into [s][d][48]  (off = col + d)
    #pragma unroll
    for (int t = 0; t < 9; ++t) {
        int col = t * 16 + lm;
        if (col < OUTD) {
            int d = (col >= 94) ? 2 : ((col >= 47) ? 1 : 0);
            int off = d * PRS + (col - d * 47);
            #pragma unroll
            for (int ar = 0; ar < 2; ++ar)
                #pragma unroll
                for (int r = 0; r < 4; ++r) {
                    int s = sbase + ar * 16 + lq * 4 + r;
                    shp16[s * SRS + off] = (f16)acc3[ar][t][r];
                }
        }
    }
    __syncthreads();

    // ---- Phase 4: per (sample, dim): softmax -> bin scan -> RQS ----
    for (int pidx = tid; pidx < TILE * 3; pidx += NT) {
        const int s = pidx / 3, d = pidx - s * 3;
        const int g = g0 + s;
        if (g < N) {
            const f16* pr = &shp16[s * SRS + d * PRS];
            f16x8 v0 = *(const f16x8*)&pr[0];
            f16x8 v1 = *(const f16x8*)&pr[8];
            f16x8 v2 = *(const f16x8*)&pr[16];
            f16x8 v3 = *(const f16x8*)&pr[24];
            f16x8 v4 = *(const f16x8*)&pr[32];
            f16x8 v5 = *(const f16x8*)&pr[40];
            float wv_[16], hv[16], dl[15];
            #pragma unroll
            for (int i = 0; i < 8; ++i) {
                wv_[i] = (float)v0[i]; wv_[8 + i] = (float)v1[i];
                hv[i]  = (float)v2[i]; hv[8 + i]  = (float)v3[i];
            }
            #pragma unroll
            for (int i = 0; i < 8; ++i) dl[i] = (float)v4[i];
            #pragma unroll
            for (int i = 0; i < 7; ++i) dl[8 + i] = (float)v5[i];

            float sw = 0.f, sh = 0.f;
            #pragma unroll
            for (int i = 0; i < 16; ++i) { wv_[i] = __expf(wv_[i]); sw += wv_[i]; }
            #pragma unroll
            for (int i = 0; i < 16; ++i) { hv[i]  = __expf(hv[i]);  sh += hv[i]; }
            float cwn = 10.f * __builtin_amdgcn_rcpf(sw);
            float chn = 10.f * __builtin_amdgcn_rcpf(sh);
            #pragma unroll
            for (int i = 0; i < 16; ++i) { wv_[i] *= cwn; hv[i] *= chn; }

            float xv = x[g * 6 + d];
            bool oob = (xv <= -BND) || (xv >= BND);
            float xm = oob ? -BND : xv;

            float cumx = -BND + wv_[0], cumy = -BND + hv[0];
            float xk_b = -BND, yk_b = -BND;
            float wk = wv_[0], hk = hv[0];
            float d0l = T1, d1l = dl[0];
            #pragma unroll
            for (int i = 1; i < 16; ++i) {
                bool ge = (xm >= cumx);
                if (ge) {
                    xk_b = cumx; yk_b = cumy;
                    wk = wv_[i]; hk = hv[i];
                    d0l = dl[i - 1];
                    d1l = (i < 15) ? dl[i] : T1;
                }
                cumx += wv_[i]; cumy += hv[i];
            }
            float d0 = (d0l > 15.f) ? d0l : __logf(1.f + __expf(d0l));
            float d1 = (d1l > 15.f) ? d1l : __logf(1.f + __expf(d1l));

            float rwk = __builtin_amdgcn_rcpf(wk);
            float sk = hk * rwk;
            float relx = (xm - xk_b) * rwk;
            relx = fminf(fmaxf(relx, 0.f), 1.f);
            float r1 = relx * (1.f - relx);
            float den = sk + (d1 + d0 - 2.f * sk) * r1;
            float iden = __builtin_amdgcn_rcpf(den);
            float num = hk * (sk * relx * relx + d0 * r1);
            float y = yk_b + num * iden;
            float omr = 1.f - relx;
            float arg = d1 * relx * relx + 2.f * sk * r1 + d0 * omr * omr;
            float ratio = sk * iden;
            float ld = __logf(ratio * ratio * arg);
            if (oob) { y = xv; ld = 0.f; }

            out_y[g * 6 + d] = y;
            out_y[g * 6 + 3 + d] = x[g * 6 + 3 + d];   // upper pass-through (fp32)
            shld[s * 3 + d] = ld;
        }
    }
    __syncthreads();

    // ---- Phase 5: reduce log-det over the 3 dims ----
    if (tid < TILE) {
        int g = g0 + tid;
        if (g < N)
            out_ld[g] = shld[tid * 3] + shld[tid * 3 + 1] + shld[tid * 3 + 2];
    }
}

extern "C" void kernel_launch(void* const* d_in, const int* in_sizes, int n_in,
                              void* d_out, int out_size, void* d_ws, size_t ws_size,
                              hipStream_t stream) {
    const float* x  = (const float*)d_in[0];
    const float* c  = (const float*)d_in[1];
    const float* W1 = (const float*)d_in[2];
    const float* b1 = (const float*)d_in[3];
    const float* W2 = (const float*)d_in[4];
    const float* b2 = (const float*)d_in[5];
    const float* W3 = (const float*)d_in[6];
    const float* b3 = (const float*)d_in[7];

    const int N = in_sizes[0] / 6;              // 500000
    float* out_y  = (float*)d_out;
    float* out_ld = (float*)d_out + (size_t)N * 6;

    bf16* W1p = (bf16*)d_ws;
    bf16* W2p = W1p + W1P_ELEMS;
    bf16* W3p = W2p + W2P_ELEMS;

    int nfrag = 512 + 2048 + 2304;              // 4864 fragments
    nsc_prepack<<<(nfrag + 255) / 256, 256, 0, stream>>>(W1, W2, W3, W1p, W2p, W3p);

    int nblocks = (N + TILE - 1) / TILE;        // 3907
    nsc_main<<<nblocks, NT, 0, stream>>>(x, c, W1p, b1, W2p, b2, W3p, b3,
                                         out_y, out_ld, N);
}